// Round 13
// baseline (134.116 us; speedup 1.0000x reference)
//
#include <hip/hip_runtime.h>
#include <stdint.h>

#define NROW 8192
#define DIM  512
#define NOUT 16
#define GAMMA 0.001f
// exp(2*gamma*c) = exp2(c * 2*gamma*log2(e))
#define EXP2S (2.0f * GAMMA * 1.44269504088896340736f)
#define SC1 0x7F7F7F7F   // e8m0 scale bytes = 127 -> 2^0 = 1.0 (unit scale)

typedef __bf16 bf16_t;
typedef bf16_t bf16x4_t __attribute__((ext_vector_type(4)));
typedef bf16_t bf16x8_t __attribute__((ext_vector_type(8)));
typedef float  floatx4_t __attribute__((ext_vector_type(4)));
typedef int    intx4_t  __attribute__((ext_vector_type(4)));
typedef int    intx8_t  __attribute__((ext_vector_type(8)));

// async global->LDS, 16 B/lane. LDS dest is wave-uniform base + lane*16.
__device__ __forceinline__ void async_copy16(const void* g, const void* l) {
    __builtin_amdgcn_global_load_lds(
        (__attribute__((address_space(1))) void*)(uintptr_t)g,
        (__attribute__((address_space(3))) void*)(uint32_t)(uintptr_t)l,
        16, 0, 0);
}

// two coalesced dwordx4 -> one 32B MFMA operand
__device__ __forceinline__ intx8_t ld_frag(const uint8_t* p) {
    const intx4_t lo = *(const intx4_t*)(p);
    const intx4_t hi = *(const intx4_t*)(p + 16);
    return __builtin_shufflevector(lo, hi, 0, 1, 2, 3, 4, 5, 6, 7);
}

// ---------- prep: fp32 -> fp8 e4m3; X in MFMA-packed layout, T row-major ----
// X packed for mfma_scale_16x16x128 B-operand: 16-row tile nt, k-group g:
// offset = ((nt*4+g)*64 + lane)*32 + j, lane = quad*16 + (row&15),
// k = g*128 + quad*32 + j. Frag load = two coalesced dwordx4 at lane*32(+16).
__global__ __launch_bounds__(256) void prep_convert(
    const float* __restrict__ X, const float* __restrict__ T,
    const float* __restrict__ alpha,
    uint8_t* __restrict__ X2, uint8_t* __restrict__ Tf,
    float* __restrict__ xfac, bf16_t* __restrict__ alphaTp)
{
    const int w = threadIdx.x >> 6, lane = threadIdx.x & 63;
    const int row = blockIdx.x * 4 + w;              // 0..16383
    const bool is_test = row < NROW;
    const float* src = is_test ? X : T;
    const int r = is_test ? row : row - NROW;
    // lane owns floats [lane*8, lane*8+8) -> one 8-byte fp8 chunk
    const float4* s4 = (const float4*)(src + (size_t)r * DIM);
    const float4 v0 = s4[lane * 2];
    const float4 v1 = s4[lane * 2 + 1];
    float ss = v0.x*v0.x + v0.y*v0.y + v0.z*v0.z + v0.w*v0.w
             + v1.x*v1.x + v1.y*v1.y + v1.z*v1.z + v1.w*v1.w;
    int lo = __builtin_amdgcn_cvt_pk_fp8_f32(v0.x, v0.y, 0, false);
    lo     = __builtin_amdgcn_cvt_pk_fp8_f32(v0.z, v0.w, lo, true);
    int hi = __builtin_amdgcn_cvt_pk_fp8_f32(v1.x, v1.y, 0, false);
    hi     = __builtin_amdgcn_cvt_pk_fp8_f32(v1.z, v1.w, hi, true);
    if (is_test) {
        // k0 = lane*8: g = lane>>4, quad = (lane>>2)&3, j = (lane&3)*8
        const size_t off = ((size_t)(((r >> 4) << 2) + (lane >> 4)) << 11)
                         + (size_t)((((lane >> 2) & 3) * 16 + (r & 15)) * 32
                                    + (lane & 3) * 8);
        *(int2*)(X2 + off) = make_int2(lo, hi);
    } else {
        *(int2*)(Tf + (size_t)r * DIM + lane * 8) = make_int2(lo, hi);
    }
#pragma unroll
    for (int m = 32; m > 0; m >>= 1) ss += __shfl_xor(ss, m, 64);
    const float f = __expf(-GAMMA * ss);             // all lanes hold the sum
    if (is_test) {
        if (lane == 0) xfac[r] = f;
    } else if (lane < 16) {
        // alphaT'[o][j] = exp(-g*||y_j||^2) * alpha[j][o]
        alphaTp[(size_t)lane * NROW + r] = (bf16_t)(alpha[r * 16 + lane] * f);
    }
}

// ---------- main: MX fp8 K=128; T via LDS dbuf, X via packed-global frags ----
// r10's wall: LDS frag-read pipe, not MFMA (14.4us busy). Hybrid: A(T) keeps
// the proven 16KB-dbuf staging; B(X) frags load straight from packed global
// (L1/L2-resident, coalesced) with a 32-reg 1-group-ahead prefetch. Halves
// ds_read traffic + staging DMA. Arch-VGPR live set kept < 128 (r4/r11/r12
// lesson: acc must stay floatx4 -> AGPR side of the unified file).
#define TPT 4        // train tiles per block (16 chunks x 4 tiles = 8192)
#define KLD2 72      // padded row stride (bf16) of per-wave K'' tile

__global__ __launch_bounds__(256, 2) void rbf_main(
    const uint8_t* __restrict__ X2, const uint8_t* __restrict__ Tf,
    const bf16_t* __restrict__ alphaTp, const float* __restrict__ xfac,
    float* __restrict__ out)
{
    // T dbuf: buf b at b*16384 (128 rows x 128B k-slice); kw 4x9216 B unions
    // on top (written only after the post-K-loop barrier, read before the next
    // restage barrier). Total 36864 B.
    __shared__ __align__(16) unsigned char smem[4 * 64 * KLD2 * 2];

    const int tid = threadIdx.x;
    const int w = tid >> 6, lane = tid & 63;
    const int wm = w >> 1, wn = w & 1;               // train half / test half
    const int quad = lane >> 4, l15 = lane & 15;

    const int rb = blockIdx.x;                       // 0..63  test block (XCD = rb%8)
    const int chunk = blockIdx.y;                    // 0..15  train chunk
    const int row0 = rb * 128;
    const int cb0 = chunk * (TPT * 128);

    // T staging: s_row = tid>>3 (0..31 per issue), unit = tid&7,
    // global unit = (tid&7) ^ (s_row&7)  (XOR swizzle)
    const int s_row = tid >> 3;
    const int s_ub = (((tid & 7) ^ (s_row & 7)) * 16);
    const uint8_t* gTp = Tf + (size_t)(cb0 + s_row) * DIM + s_ub;
    const unsigned ldsW = (unsigned)(w << 10);       // wave base in each 4KB slab

    const int sw = l15 & 7;                          // frag-read row swizzle key
    const int ub0 = ((2 * quad) ^ sw) * 16;          // physical lo-half unit
    const int ub1 = ((2 * quad + 1) ^ sw) * 16;      // physical hi-half unit

    // X packed frag pointers: n-tile nt = rb*8 + wn*4 + ni, g stride 2048
    const uint8_t* xg[4];
#pragma unroll
    for (int ni = 0; ni < 4; ++ni)
        xg[ni] = X2 + (((size_t)((rb * 8 + wn * 4 + ni) * 4)) << 11) + lane * 32;

    const floatx4_t vzero = {0.f, 0.f, 0.f, 0.f};
    floatx4_t oacc[4];
#pragma unroll
    for (int i = 0; i < 4; ++i) oacc[i] = vzero;

    bf16_t* kw = (bf16_t*)smem + w * (64 * KLD2);    // wave-private K'' region

    // prefetch X frags for g=0 (latency covered by first staging barrier)
    intx8_t xc[4], xn[4];
#pragma unroll
    for (int ni = 0; ni < 4; ++ni) xc[ni] = ld_frag(xg[ni]);

    for (int t = 0; t < TPT; ++t) {
        const int cb = cb0 + t * 128;
        const uint8_t* gTt = gTp + (size_t)t * 128 * DIM;

        floatx4_t acc[4][4];
#pragma unroll
        for (int i = 0; i < 4; ++i)
#pragma unroll
            for (int j = 0; j < 4; ++j) acc[i][j] = vzero;

        __syncthreads();             // prev kw reads done before restage
        // prime: T k-group 0 -> buf0
#pragma unroll
        for (int i = 0; i < 4; ++i)
            async_copy16(gTt + (size_t)i * 16384, smem + i * 4096 + ldsW);

#pragma unroll
        for (int g = 0; g < 4; ++g) {
            __syncthreads();         // drains vmcnt: T buf[g&1] landed (covered)
            if (g < 3) {             // issue T g+1; prefetch X g+1
                const unsigned bb = ((g + 1) & 1) * 16384u;
                const int kb = (g + 1) * 128;
#pragma unroll
                for (int i = 0; i < 4; ++i)
                    async_copy16(gTt + (size_t)i * 16384 + kb,
                                 smem + bb + i * 4096 + ldsW);
#pragma unroll
                for (int ni = 0; ni < 4; ++ni)
                    xn[ni] = ld_frag(xg[ni] + ((g + 1) << 11));
            } else if (t + 1 < TPT) {
#pragma unroll
                for (int ni = 0; ni < 4; ++ni)   // g=0 of next tile (same X)
                    xn[ni] = ld_frag(xg[ni]);
            }
            const unsigned char* bufc = smem + (g & 1) * 16384;
#pragma unroll
            for (int mi = 0; mi < 4; ++mi) {
                const int rA = wm * 64 + mi * 16 + l15;
                const intx4_t alo = *(const intx4_t*)(bufc + rA * 128 + ub0);
                const intx4_t ahi = *(const intx4_t*)(bufc + rA * 128 + ub1);
                const intx8_t ta = __builtin_shufflevector(alo, ahi, 0, 1, 2, 3, 4, 5, 6, 7);
#pragma unroll
                for (int ni = 0; ni < 4; ++ni)
                    acc[mi][ni] = __builtin_amdgcn_mfma_scale_f32_16x16x128_f8f6f4(
                        ta, xc[ni], acc[mi][ni], 0, 0, 0, SC1, 0, SC1);
            }
#pragma unroll
            for (int ni = 0; ni < 4; ++ni) xc[ni] = xn[ni];
        }

        __syncthreads();   // all frag reads done before kw overwrites bufs
        // K'' = exp(2*gamma*cross), bf16, test-major kw[test][train], 8B stores
        // acc[mi][ni][r] = cross[train = mi*16+quad*4+r][test = ni*16+l15]
#pragma unroll
        for (int ni = 0; ni < 4; ++ni)
#pragma unroll
            for (int mi = 0; mi < 4; ++mi) {
                bf16x4_t pk;
#pragma unroll
                for (int r = 0; r < 4; ++r)
                    pk[r] = (bf16_t)__builtin_amdgcn_exp2f(acc[mi][ni][r] * EXP2S);
                *(bf16x4_t*)(kw + (ni * 16 + l15) * KLD2 + mi * 16 + quad * 4) = pk;
            }
        // no barrier: each wave reads only its own kw region (in-wave lgkmcnt)

        // epilogue: oacc[ni] += K''[test 16(ni) x train 64] @ alpha'[64 x 16]
#pragma unroll
        for (int ks = 0; ks < 2; ++ks) {
            const bf16x8_t bv = *(const bf16x8_t*)(alphaTp + (size_t)l15 * NROW
                                                   + cb + wm * 64 + ks * 32 + quad * 8);
#pragma unroll
            for (int ni = 0; ni < 4; ++ni) {
                const bf16x8_t av = *(const bf16x8_t*)(kw + (ni * 16 + l15) * KLD2
                                                       + ks * 32 + quad * 8);
                oacc[ni] = __builtin_amdgcn_mfma_f32_16x16x32_bf16(av, bv, oacc[ni], 0, 0, 0);
            }
        }
        // next t: leading __syncthreads() protects kw reads vs restaging
    }

    // reduce the two train halves (wm=0,1) through LDS, then atomicAdd to out
    __syncthreads();
    float* stash = (float*)smem;
    if (wm == 1) {
#pragma unroll
        for (int ni = 0; ni < 4; ++ni)
            *(floatx4_t*)(stash + wn * 1024 + ni * 256 + lane * 4) = oacc[ni];
    }
    __syncthreads();
    if (wm == 0) {
#pragma unroll
        for (int ni = 0; ni < 4; ++ni) {
            const floatx4_t o2 = *(const floatx4_t*)(stash + wn * 1024 + ni * 256 + lane * 4);
            const int trow = row0 + wn * 64 + ni * 16 + quad * 4;
            const float4 xf = *(const float4*)(xfac + trow);
            atomicAdd(out + (size_t)(trow + 0) * NOUT + l15, (oacc[ni][0] + o2[0]) * xf.x);
            atomicAdd(out + (size_t)(trow + 1) * NOUT + l15, (oacc[ni][1] + o2[1]) * xf.y);
            atomicAdd(out + (size_t)(trow + 2) * NOUT + l15, (oacc[ni][2] + o2[2]) * xf.z);
            atomicAdd(out + (size_t)(trow + 3) * NOUT + l15, (oacc[ni][3] + o2[3]) * xf.w);
        }
    }
}

extern "C" void kernel_launch(void* const* d_in, const int* in_sizes, int n_in,
                              void* d_out, int out_size, void* d_ws, size_t ws_size,
                              hipStream_t stream) {
    (void)in_sizes; (void)n_in; (void)out_size; (void)ws_size;
    const float* X     = (const float*)d_in[0];
    const float* T     = (const float*)d_in[1];
    const float* alpha = (const float*)d_in[2];

    char* ws = (char*)d_ws;
    uint8_t* X2     = (uint8_t*)ws;                                  // 4 MB packed
    uint8_t* Tf     = (uint8_t*)(ws + (8u << 20));                   // 4 MB row-major
    float*   xfac   = (float*)(ws + (16u << 20));                    // 32 KB
    bf16_t*  alphaTp= (bf16_t*)(ws + (16u << 20) + (64u << 10));     // 256 KB
    float*   out    = (float*)d_out;

    hipMemsetAsync(out, 0, (size_t)NROW * NOUT * sizeof(float), stream);
    prep_convert<<<4096, 256, 0, stream>>>(X, T, alpha, X2, Tf, xfac, alphaTp);
    dim3 grid(64, 16);   // x = rb (XCD affinity for X), y = chunk
    rbf_main<<<grid, 256, 0, stream>>>(X2, Tf, alphaTp, xfac, out);
}

// Round 14
// 128.212 us; speedup vs baseline: 1.0460x; 1.0460x over previous
//
#include <hip/hip_runtime.h>
#include <stdint.h>

#define NROW 8192
#define DIM  512
#define NOUT 16
#define GAMMA 0.001f
// exp(2*gamma*c) = exp2(c * 2*gamma*log2(e))
#define EXP2S (2.0f * GAMMA * 1.44269504088896340736f)
#define SC1 0x7F7F7F7F   // e8m0 scale bytes = 127 -> 2^0 = 1.0 (unit scale)

typedef __bf16 bf16_t;
typedef bf16_t bf16x4_t __attribute__((ext_vector_type(4)));
typedef bf16_t bf16x8_t __attribute__((ext_vector_type(8)));
typedef float  floatx4_t __attribute__((ext_vector_type(4)));
typedef int    intx4_t  __attribute__((ext_vector_type(4)));
typedef int    intx8_t  __attribute__((ext_vector_type(8)));

// async global->LDS, 16 B/lane. LDS dest is wave-uniform base + lane*16.
__device__ __forceinline__ void async_copy16(const void* g, const void* l) {
    __builtin_amdgcn_global_load_lds(
        (__attribute__((address_space(1))) void*)(uintptr_t)g,
        (__attribute__((address_space(3))) void*)(uint32_t)(uintptr_t)l,
        16, 0, 0);
}

// two coalesced dwordx4 -> one 32B MFMA operand
__device__ __forceinline__ intx8_t ld_frag(const uint8_t* p) {
    const intx4_t lo = *(const intx4_t*)(p);
    const intx4_t hi = *(const intx4_t*)(p + 16);
    return __builtin_shufflevector(lo, hi, 0, 1, 2, 3, 4, 5, 6, 7);
}

// ---------- prep: fp32 -> fp8 e4m3; X in MFMA-packed layout, T row-major ----
// X packed for mfma_scale_16x16x128 B-operand (verified r13): 16-row tile nt,
// k-group g: offset = ((nt*4+g)*64 + lane)*32 + j, lane = quad*16 + (row&15),
// k = g*128 + quad*32 + j. Frag load = two coalesced dwordx4 at lane*32(+16).
// Blocks 0..511 also zero d_out (replaces the hipMemsetAsync graph node).
__global__ __launch_bounds__(256) void prep_convert(
    const float* __restrict__ X, const float* __restrict__ T,
    const float* __restrict__ alpha,
    uint8_t* __restrict__ X2, uint8_t* __restrict__ Tf,
    float* __restrict__ xfac, bf16_t* __restrict__ alphaTp,
    float* __restrict__ out)
{
    const int w = threadIdx.x >> 6, lane = threadIdx.x & 63;
    if (blockIdx.x < 512) out[blockIdx.x * 256 + threadIdx.x] = 0.f;  // 512*256 = NROW*NOUT
    const int row = blockIdx.x * 4 + w;              // 0..16383
    const bool is_test = row < NROW;
    const float* src = is_test ? X : T;
    const int r = is_test ? row : row - NROW;
    // lane owns floats [lane*8, lane*8+8) -> one 8-byte fp8 chunk
    const float4* s4 = (const float4*)(src + (size_t)r * DIM);
    const float4 v0 = s4[lane * 2];
    const float4 v1 = s4[lane * 2 + 1];
    float ss = v0.x*v0.x + v0.y*v0.y + v0.z*v0.z + v0.w*v0.w
             + v1.x*v1.x + v1.y*v1.y + v1.z*v1.z + v1.w*v1.w;
    int lo = __builtin_amdgcn_cvt_pk_fp8_f32(v0.x, v0.y, 0, false);
    lo     = __builtin_amdgcn_cvt_pk_fp8_f32(v0.z, v0.w, lo, true);
    int hi = __builtin_amdgcn_cvt_pk_fp8_f32(v1.x, v1.y, 0, false);
    hi     = __builtin_amdgcn_cvt_pk_fp8_f32(v1.z, v1.w, hi, true);
    if (is_test) {
        // k0 = lane*8: g = lane>>4, quad = (lane>>2)&3, j = (lane&3)*8
        const size_t off = ((size_t)(((r >> 4) << 2) + (lane >> 4)) << 11)
                         + (size_t)((((lane >> 2) & 3) * 16 + (r & 15)) * 32
                                    + (lane & 3) * 8);
        *(int2*)(X2 + off) = make_int2(lo, hi);
    } else {
        *(int2*)(Tf + (size_t)r * DIM + lane * 8) = make_int2(lo, hi);
    }
#pragma unroll
    for (int m = 32; m > 0; m >>= 1) ss += __shfl_xor(ss, m, 64);
    const float f = __expf(-GAMMA * ss);             // all lanes hold the sum
    if (is_test) {
        if (lane == 0) xfac[r] = f;
    } else if (lane < 16) {
        // alphaT'[o][j] = exp(-g*||y_j||^2) * alpha[j][o]
        alphaTp[(size_t)lane * NROW + r] = (bf16_t)(alpha[r * 16 + lane] * f);
    }
}

// ---------- main: MX fp8 K=128; T via LDS dbuf, X via packed-global frags ----
// r13 validated the hybrid but spilled (xc+xn = 64 regs). Single xc[4] set
// (32 regs) loaded right after the barrier: its ~200cyc L2 latency overlaps
// the 8 A-frag ds_reads + cross-wave issue. Arch-VGPR live set ~90 < 128 ->
// no spill (r4/r11/r12/r13 law: acc stays floatx4 -> AGPR side; arch side
// must stay under ~128 when 80 AGPRs are live).
#define TPT 4        // train tiles per block (16 chunks x 4 tiles = 8192)
#define KLD2 72      // padded row stride (bf16) of per-wave K'' tile

__global__ __launch_bounds__(256, 2) void rbf_main(
    const uint8_t* __restrict__ X2, const uint8_t* __restrict__ Tf,
    const bf16_t* __restrict__ alphaTp, const float* __restrict__ xfac,
    float* __restrict__ out)
{
    // T dbuf: buf b at b*16384 (128 rows x 128B k-slice); kw 4x9216 B unions
    // on top (written only after the post-K-loop barrier, read before the next
    // restage barrier). Total 36864 B.
    __shared__ __align__(16) unsigned char smem[4 * 64 * KLD2 * 2];

    const int tid = threadIdx.x;
    const int w = tid >> 6, lane = tid & 63;
    const int wm = w >> 1, wn = w & 1;               // train half / test half
    const int quad = lane >> 4, l15 = lane & 15;

    const int rb = blockIdx.x;                       // 0..63  test block (XCD = rb%8)
    const int chunk = blockIdx.y;                    // 0..15  train chunk
    const int row0 = rb * 128;
    const int cb0 = chunk * (TPT * 128);

    // T staging: s_row = tid>>3 (0..31 per issue), unit = tid&7,
    // global unit = (tid&7) ^ (s_row&7)  (XOR swizzle)
    const int s_row = tid >> 3;
    const int s_ub = (((tid & 7) ^ (s_row & 7)) * 16);
    const uint8_t* gTp = Tf + (size_t)(cb0 + s_row) * DIM + s_ub;
    const unsigned ldsW = (unsigned)(w << 10);       // wave base in each 4KB slab

    const int sw = l15 & 7;                          // frag-read row swizzle key
    const int ub0 = ((2 * quad) ^ sw) * 16;          // physical lo-half unit
    const int ub1 = ((2 * quad + 1) ^ sw) * 16;      // physical hi-half unit

    // X packed frag base: n-tile nt = rb*8 + wn*4 + ni (ni stride 4<<11), g stride 2048
    const uint8_t* xgb = X2 + (((size_t)((rb * 8 + wn * 4) * 4)) << 11) + lane * 32;

    const floatx4_t vzero = {0.f, 0.f, 0.f, 0.f};
    floatx4_t oacc[4];
#pragma unroll
    for (int i = 0; i < 4; ++i) oacc[i] = vzero;

    bf16_t* kw = (bf16_t*)smem + w * (64 * KLD2);    // wave-private K'' region

    for (int t = 0; t < TPT; ++t) {
        const int cb = cb0 + t * 128;
        const uint8_t* gTt = gTp + (size_t)t * 128 * DIM;

        floatx4_t acc[4][4];
#pragma unroll
        for (int i = 0; i < 4; ++i)
#pragma unroll
            for (int j = 0; j < 4; ++j) acc[i][j] = vzero;

        __syncthreads();             // prev kw reads done before restage
        // prime: T k-group 0 -> buf0
#pragma unroll
        for (int i = 0; i < 4; ++i)
            async_copy16(gTt + (size_t)i * 16384, smem + i * 4096 + ldsW);

#pragma unroll
        for (int g = 0; g < 4; ++g) {
            __syncthreads();         // drains vmcnt: T buf[g&1] landed (covered)
            // X frags for this group: issue first so L2 latency overlaps the
            // A-frag ds_reads below (single set, 32 VGPRs -- no spill)
            intx8_t xc[4];
#pragma unroll
            for (int ni = 0; ni < 4; ++ni)
                xc[ni] = ld_frag(xgb + (((size_t)ni * 4 + g) << 11));
            if (g < 3) {             // issue T g+1 into the other buffer
                const unsigned bb = ((g + 1) & 1) * 16384u;
                const int kb = (g + 1) * 128;
#pragma unroll
                for (int i = 0; i < 4; ++i)
                    async_copy16(gTt + (size_t)i * 16384 + kb,
                                 smem + bb + i * 4096 + ldsW);
            }
            const unsigned char* bufc = smem + (g & 1) * 16384;
#pragma unroll
            for (int mi = 0; mi < 4; ++mi) {
                const int rA = wm * 64 + mi * 16 + l15;
                const intx4_t alo = *(const intx4_t*)(bufc + rA * 128 + ub0);
                const intx4_t ahi = *(const intx4_t*)(bufc + rA * 128 + ub1);
                const intx8_t ta = __builtin_shufflevector(alo, ahi, 0, 1, 2, 3, 4, 5, 6, 7);
#pragma unroll
                for (int ni = 0; ni < 4; ++ni)
                    acc[mi][ni] = __builtin_amdgcn_mfma_scale_f32_16x16x128_f8f6f4(
                        ta, xc[ni], acc[mi][ni], 0, 0, 0, SC1, 0, SC1);
            }
        }

        __syncthreads();   // all frag reads done before kw overwrites bufs
        // K'' = exp(2*gamma*cross), bf16, test-major kw[test][train], 8B stores
        // acc[mi][ni][r] = cross[train = mi*16+quad*4+r][test = ni*16+l15]
#pragma unroll
        for (int ni = 0; ni < 4; ++ni)
#pragma unroll
            for (int mi = 0; mi < 4; ++mi) {
                bf16x4_t pk;
#pragma unroll
                for (int r = 0; r < 4; ++r)
                    pk[r] = (bf16_t)__builtin_amdgcn_exp2f(acc[mi][ni][r] * EXP2S);
                *(bf16x4_t*)(kw + (ni * 16 + l15) * KLD2 + mi * 16 + quad * 4) = pk;
            }
        // no barrier: each wave reads only its own kw region (in-wave lgkmcnt)

        // epilogue: oacc[ni] += K''[test 16(ni) x train 64] @ alpha'[64 x 16]
#pragma unroll
        for (int ks = 0; ks < 2; ++ks) {
            const bf16x8_t bv = *(const bf16x8_t*)(alphaTp + (size_t)l15 * NROW
                                                   + cb + wm * 64 + ks * 32 + quad * 8);
#pragma unroll
            for (int ni = 0; ni < 4; ++ni) {
                const bf16x8_t av = *(const bf16x8_t*)(kw + (ni * 16 + l15) * KLD2
                                                       + ks * 32 + quad * 8);
                oacc[ni] = __builtin_amdgcn_mfma_f32_16x16x32_bf16(av, bv, oacc[ni], 0, 0, 0);
            }
        }
        // next t: leading __syncthreads() protects kw reads vs restaging
    }

    // reduce the two train halves (wm=0,1) through LDS, then atomicAdd to out
    __syncthreads();
    float* stash = (float*)smem;
    if (wm == 1) {
#pragma unroll
        for (int ni = 0; ni < 4; ++ni)
            *(floatx4_t*)(stash + wn * 1024 + ni * 256 + lane * 4) = oacc[ni];
    }
    __syncthreads();
    if (wm == 0) {
#pragma unroll
        for (int ni = 0; ni < 4; ++ni) {
            const floatx4_t o2 = *(const floatx4_t*)(stash + wn * 1024 + ni * 256 + lane * 4);
            const int trow = row0 + wn * 64 + ni * 16 + quad * 4;
            const float4 xf = *(const float4*)(xfac + trow);
            atomicAdd(out + (size_t)(trow + 0) * NOUT + l15, (oacc[ni][0] + o2[0]) * xf.x);
            atomicAdd(out + (size_t)(trow + 1) * NOUT + l15, (oacc[ni][1] + o2[1]) * xf.y);
            atomicAdd(out + (size_t)(trow + 2) * NOUT + l15, (oacc[ni][2] + o2[2]) * xf.z);
            atomicAdd(out + (size_t)(trow + 3) * NOUT + l15, (oacc[ni][3] + o2[3]) * xf.w);
        }
    }
}

extern "C" void kernel_launch(void* const* d_in, const int* in_sizes, int n_in,
                              void* d_out, int out_size, void* d_ws, size_t ws_size,
                              hipStream_t stream) {
    (void)in_sizes; (void)n_in; (void)out_size; (void)ws_size;
    const float* X     = (const float*)d_in[0];
    const float* T     = (const float*)d_in[1];
    const float* alpha = (const float*)d_in[2];

    char* ws = (char*)d_ws;
    uint8_t* X2     = (uint8_t*)ws;                                  // 4 MB packed
    uint8_t* Tf     = (uint8_t*)(ws + (8u << 20));                   // 4 MB row-major
    float*   xfac   = (float*)(ws + (16u << 20));                    // 32 KB
    bf16_t*  alphaTp= (bf16_t*)(ws + (16u << 20) + (64u << 10));     // 256 KB
    float*   out    = (float*)d_out;

    prep_convert<<<4096, 256, 0, stream>>>(X, T, alpha, X2, Tf, xfac, alphaTp, out);
    dim3 grid(64, 16);   // x = rb (XCD affinity for X), y = chunk
    rbf_main<<<grid, 256, 0, stream>>>(X2, Tf, alphaTp, xfac, out);
}